// Round 2
// 296.578 us; speedup vs baseline: 1.3117x; 1.3117x over previous
//
#include <hip/hip_runtime.h>

// Problem constants
#define IN_F   4096
#define OUT_F  4096
#define RK     32      // R_MIN
#define NB1    2048    // B1
#define LBATCH 10240   // B1 + B2*MULT
#define MAXB   2048    // worst-case rows per bucket
#define TILES  4       // 64-row tiles per bucket (capacity 256; n ~ 64)

typedef __attribute__((ext_vector_type(2))) __fp16 h2;
typedef __attribute__((ext_vector_type(8))) __fp16 h8;
typedef __attribute__((ext_vector_type(4))) float  f4;

// ws layout (ints): cnt[64] | list[64*2048] | r[10240*32] f32

__global__ __launch_bounds__(256) void bin_rows(const int* __restrict__ wids,
                                                int* cnt1, int* cnt2,
                                                int* list1, int* list2) {
    int t = blockIdx.x * 256 + threadIdx.x;   // 0..4095
    if (t < NB1) {
        int w = wids[t];
        int p = atomicAdd(&cnt1[w], 1);
        list1[w * MAXB + p] = t;
    } else {
        int i = t - NB1;
        int j = (wids[NB1 + 4 * i] - 32) >> 2;
        int p = atomicAdd(&cnt2[j], 1);
        list2[j * MAXB + p] = i;
    }
}

// ---------------- Stage 1: r[64 x NC] += X[64 x 256] @ Amat[256 x NC]  (MFMA f16)
// P2=false: bucket g (adapter g), NC=32.  P2=true: group g, adapters 32+4g+m, NC=128.
// Wave w owns rows 16w..16w+15. X loaded global->frag (8 contig k / lane).
// Amat transposed into LDS [C][k] halves, double-buffered, 1 barrier/step.
template<bool P2>
__device__ __forceinline__ void s1_body(const float* __restrict__ x,
                                        const float* __restrict__ A,
                                        float* __restrict__ r,
                                        __fp16 (*At)[128][40],
                                        const int* rowid,
                                        int g, int k0, int tz, int n) {
    constexpr int NT = P2 ? 8 : 2;     // 16-col tiles
    constexpr int KL = P2 ? 16 : 4;    // k-rows staged per thread per 32-k step

    int t    = threadIdx.x;
    int lane = t & 63;
    int w    = t >> 6;
    int m    = lane & 15;
    int kg   = lane >> 4;

    // X fragment source: 8 contiguous f32 per lane per step
    int xr = rowid[16 * w + m];
    const float* xb = x + (size_t)(P2 ? NB1 + xr : xr) * IN_F + k0 + kg * 8;

    // A staging: thread owns column C, k-rows [kh*KL, kh*KL+KL)
    int C  = t & (P2 ? 127 : 31);
    int kh = t >> (P2 ? 7 : 5);
    const float* asrc;
    if constexpr (P2)
        asrc = A + ((size_t)(32 + 4 * g + (C >> 5)) * IN_F + k0 + kh * KL) * RK + (C & 31);
    else
        asrc = A + ((size_t)g * IN_F + k0 + kh * KL) * RK + C;

    f4 acc[NT];
    #pragma unroll
    for (int ct = 0; ct < NT; ++ct) acc[ct] = (f4){0.f, 0.f, 0.f, 0.f};

    // prologue: X step0 + stage A step0 into buf 0
    f4 xf0 = *(const f4*)xb;
    f4 xf1 = *(const f4*)(xb + 4);
    {
        float v[KL];
        #pragma unroll
        for (int q = 0; q < KL; ++q) v[q] = asrc[q * RK];
        #pragma unroll
        for (int q = 0; q < KL / 2; ++q)
            *(h2*)&At[0][C][kh * KL + 2 * q] = __builtin_amdgcn_cvt_pkrtz(v[2 * q], v[2 * q + 1]);
    }
    __syncthreads();

    #pragma unroll
    for (int s = 0; s < 8; ++s) {
        // issue next-step global loads early (T14)
        float vn[KL];
        f4 nx0, nx1;
        if (s < 7) {
            const float* as2 = asrc + (size_t)(s + 1) * 32 * RK;
            #pragma unroll
            for (int q = 0; q < KL; ++q) vn[q] = as2[q * RK];
            nx0 = *(const f4*)(xb + (s + 1) * 32);
            nx1 = *(const f4*)(xb + (s + 1) * 32 + 4);
        }
        // current X fragment (exact: values are fp16-representable)
        h8 xa;
        {
            union { h8 v8; h2 h[4]; } u;
            u.h[0] = __builtin_amdgcn_cvt_pkrtz(xf0.x, xf0.y);
            u.h[1] = __builtin_amdgcn_cvt_pkrtz(xf0.z, xf0.w);
            u.h[2] = __builtin_amdgcn_cvt_pkrtz(xf1.x, xf1.y);
            u.h[3] = __builtin_amdgcn_cvt_pkrtz(xf1.z, xf1.w);
            xa = u.v8;
        }
        int b = s & 1;
        #pragma unroll
        for (int ct = 0; ct < NT; ++ct) {
            h8 bf = *(const h8*)&At[b][ct * 16 + m][kg * 8];
            acc[ct] = __builtin_amdgcn_mfma_f32_16x16x32_f16(xa, bf, acc[ct], 0, 0, 0);
        }
        // write next-step staging late
        if (s < 7) {
            #pragma unroll
            for (int q = 0; q < KL / 2; ++q)
                *(h2*)&At[b ^ 1][C][kh * KL + 2 * q] = __builtin_amdgcn_cvt_pkrtz(vn[2 * q], vn[2 * q + 1]);
            xf0 = nx0; xf1 = nx1;
        }
        __syncthreads();
    }

    // flush (k-split partial) via f32 atomics. D layout: col = lane&15, row = 4*(lane>>4)+q.
    #pragma unroll
    for (int q = 0; q < 4; ++q) {
        int br = 16 * w + 4 * kg + q;
        int it = 64 * tz + br;
        if (it < n) {
            int rid = rowid[br];
            #pragma unroll
            for (int ct = 0; ct < NT; ++ct) {
                int c = ct * 16 + m;
                size_t off = P2 ? ((size_t)(NB1 + 4 * rid + (c >> 5)) * RK + (c & 31))
                                : ((size_t)rid * RK + c);
                atomicAdd(&r[off], acc[ct][q]);
            }
        }
    }
}

__global__ __launch_bounds__(256, 3) void s1_all(const float* __restrict__ x,
                                                 const float* __restrict__ A,
                                                 const int*   __restrict__ cnt,
                                                 const int*   __restrict__ list,
                                                 float*       __restrict__ r) {
    __shared__ __align__(16) __fp16 At[2][128][40];
    __shared__ int rowid[64];
    int g  = blockIdx.x;               // 0..63: <32 part1 buckets, >=32 part2 groups
    int tz = blockIdx.z;
    int n  = cnt[g];
    if (64 * tz >= n) return;
    if (threadIdx.x < 64) {
        int it = 64 * tz + threadIdx.x;
        rowid[threadIdx.x] = list[g * MAXB + (it < n ? it : n - 1)];
    }
    __syncthreads();
    int k0 = blockIdx.y * 256;
    if (g < 32) s1_body<false>(x, A, r, At, rowid, g, k0, tz, n);
    else        s1_body<true >(x, A, r, At, rowid, g - 32, k0, tz, n);
}

// ---------------- Stage 2: Out[64 x 128] = 2 * R[64 x K] @ Bmat[K x 128]  (MFMA f16)
// P2=false: K=32 (1 step).  P2=true: K=128 = 4 adapters x 32 (4 steps).
// R loaded global->frag (r is hot in L2/L3); B transposed-staged [oc][k] in LDS.
template<bool P2>
__device__ __forceinline__ void s2_body(const float* __restrict__ r,
                                        const float* __restrict__ B,
                                        float* __restrict__ out,
                                        __fp16 (*Bt)[128][40],
                                        const int* rowid,
                                        int g, int ot, int tz, int n) {
    constexpr int NS = P2 ? 4 : 1;

    int t    = threadIdx.x;
    int lane = t & 63;
    int w    = t >> 6;
    int m    = lane & 15;
    int kg   = lane >> 4;

    int rid0 = rowid[16 * w + m];

    // issue R loads first (8 contig f32 per lane per k-step)
    f4 ra[NS], rb[NS];
    #pragma unroll
    for (int kc = 0; kc < NS; ++kc) {
        const float* rp = r + (P2 ? (size_t)(NB1 + 4 * rid0 + kc) * RK
                                  : (size_t)rid0 * RK) + kg * 8;
        ra[kc] = *(const f4*)rp;
        rb[kc] = *(const f4*)(rp + 4);
    }

    // B staging: thread owns out-col oc, k-rows [kh*16, kh*16+16)
    int oc = t & 127;
    int kh = t >> 7;
    float v[16];
    {
        int a = P2 ? (32 + 4 * g) : g;
        const float* s0 = B + ((size_t)a * RK + kh * 16) * OUT_F + ot * 128 + oc;
        #pragma unroll
        for (int q = 0; q < 16; ++q) v[q] = s0[q * OUT_F];
    }

    // R -> f16 fragments (RN casts; reference itself rounds y to f16)
    h8 rf[NS];
    #pragma unroll
    for (int kc = 0; kc < NS; ++kc) {
        h8 f;
        f[0] = (__fp16)ra[kc].x; f[1] = (__fp16)ra[kc].y;
        f[2] = (__fp16)ra[kc].z; f[3] = (__fp16)ra[kc].w;
        f[4] = (__fp16)rb[kc].x; f[5] = (__fp16)rb[kc].y;
        f[6] = (__fp16)rb[kc].z; f[7] = (__fp16)rb[kc].w;
        rf[kc] = f;
    }

    #pragma unroll
    for (int q = 0; q < 8; ++q)
        *(h2*)&Bt[0][oc][kh * 16 + 2 * q] = __builtin_amdgcn_cvt_pkrtz(v[2 * q], v[2 * q + 1]);
    __syncthreads();

    f4 acc[8];
    #pragma unroll
    for (int ct = 0; ct < 8; ++ct) acc[ct] = (f4){0.f, 0.f, 0.f, 0.f};

    #pragma unroll
    for (int kc = 0; kc < NS; ++kc) {
        float vn[16];
        if (kc < NS - 1) {
            int a = 32 + 4 * g + kc + 1;   // only P2 reaches here
            const float* sn = B + ((size_t)a * RK + kh * 16) * OUT_F + ot * 128 + oc;
            #pragma unroll
            for (int q = 0; q < 16; ++q) vn[q] = sn[q * OUT_F];
        }
        int b = kc & 1;
        #pragma unroll
        for (int ct = 0; ct < 8; ++ct) {
            h8 bf = *(const h8*)&Bt[b][ct * 16 + m][kg * 8];
            acc[ct] = __builtin_amdgcn_mfma_f32_16x16x32_f16(rf[kc], bf, acc[ct], 0, 0, 0);
        }
        if (kc < NS - 1) {
            #pragma unroll
            for (int q = 0; q < 8; ++q)
                *(h2*)&Bt[b ^ 1][oc][kh * 16 + 2 * q] = __builtin_amdgcn_cvt_pkrtz(vn[2 * q], vn[2 * q + 1]);
        }
        __syncthreads();
    }

    // store: each element written exactly once
    #pragma unroll
    for (int q = 0; q < 4; ++q) {
        int br = 16 * w + 4 * kg + q;
        int it = 64 * tz + br;
        if (it < n) {
            int orow = P2 ? (NB1 + rowid[br]) : rowid[br];
            float* op = out + (size_t)orow * OUT_F + ot * 128 + m;
            #pragma unroll
            for (int ct = 0; ct < 8; ++ct)
                op[ct * 16] = 2.f * acc[ct][q];
        }
    }
}

__global__ __launch_bounds__(256, 3) void s2_all(const float* __restrict__ r,
                                                 const float* __restrict__ B,
                                                 const int*   __restrict__ cnt,
                                                 const int*   __restrict__ list,
                                                 float*       __restrict__ out) {
    __shared__ __align__(16) __fp16 Bt[2][128][40];
    __shared__ int rowid[64];
    int g  = blockIdx.x;
    int ot = blockIdx.y;
    int tz = blockIdx.z;
    int n  = cnt[g];
    if (64 * tz >= n) return;
    if (threadIdx.x < 64) {
        int it = 64 * tz + threadIdx.x;
        rowid[threadIdx.x] = list[g * MAXB + (it < n ? it : n - 1)];
    }
    __syncthreads();
    if (g < 32) s2_body<false>(r, B, out, Bt, rowid, g, ot, tz, n);
    else        s2_body<true >(r, B, out, Bt, rowid, g - 32, ot, tz, n);
}

extern "C" void kernel_launch(void* const* d_in, const int* in_sizes, int n_in,
                              void* d_out, int out_size, void* d_ws, size_t ws_size,
                              hipStream_t stream) {
    const float* x    = (const float*)d_in[0];
    const int*   wids = (const int*)  d_in[2];
    const float* A    = (const float*)d_in[3];
    const float* Bm   = (const float*)d_in[4];
    float* out = (float*)d_out;

    int* wsI   = (int*)d_ws;
    int* cnt1  = wsI;
    int* cnt2  = wsI + 32;
    int* list1 = wsI + 64;
    int* list2 = list1 + 32 * MAXB;
    float* r   = (float*)(list2 + 32 * MAXB);

    hipMemsetAsync(cnt1, 0, 64 * sizeof(int), stream);
    hipMemsetAsync(r, 0, (size_t)LBATCH * RK * sizeof(float), stream);

    bin_rows<<<dim3(16), dim3(256), 0, stream>>>(wids, cnt1, cnt2, list1, list2);
    // merged part1+part2 per stage: cnt1/cnt2 and list1/list2 are contiguous in ws
    s1_all<<<dim3(64, 16, TILES), dim3(256), 0, stream>>>(x, A, cnt1, list1, r);
    s2_all<<<dim3(64, 32, TILES), dim3(256), 0, stream>>>(r, Bm, cnt1, list1, out);
}

// Round 3
// 292.758 us; speedup vs baseline: 1.3289x; 1.0130x over previous
//
#include <hip/hip_runtime.h>

// Problem constants
#define IN_F   4096
#define OUT_F  4096
#define RK     32      // R_MIN
#define NB1    2048    // B1
#define LBATCH 10240   // B1 + B2*MULT
#define MAXB   2048    // worst-case rows per bucket
#define TILES  4       // 64-row tiles per bucket (capacity 256; n ~ 64)
#define LRK    (LBATCH * RK)

typedef __attribute__((ext_vector_type(2))) __fp16 h2;
typedef __attribute__((ext_vector_type(8))) __fp16 h8;
typedef __attribute__((ext_vector_type(4))) float  f4;

// ws layout (ints): cnt[64] | list[64*2048] | slabs[ks][10240][32] f32

// ---------- binning: ONE block, LDS counters (no memset launches needed)
__global__ __launch_bounds__(1024) void bin_rows(const int* __restrict__ wids,
                                                 int* __restrict__ cnt,
                                                 int* __restrict__ list) {
    __shared__ int lc[64];
    int t = threadIdx.x;
    if (t < 64) lc[t] = 0;
    __syncthreads();
    for (int it = t; it < 4096; it += 1024) {
        int b, v;
        if (it < NB1) { b = wids[it]; v = it; }
        else { int i = it - NB1; b = 32 + ((wids[NB1 + 4 * i] - 32) >> 2); v = i; }
        int p = atomicAdd(&lc[b], 1);
        list[b * MAXB + p] = v;
    }
    __syncthreads();
    if (t < 64) cnt[t] = lc[t];
}

// ---------------- Stage 1: slab[64 x NC] = X[64 x KC] @ Amat[KC x NC]  (MFMA f16)
// Atomic-free: block (g, kc-chunk, tz) writes its own slab. A loaded coalesced
// (float4 along RK, k-pairs), transposed into LDS [c][k] pitch 40 with k-block
// XOR swizzle (write conflicts 32-way -> 4-way). X direct global->fragment.
template<bool P2>
__device__ __forceinline__ void s1_body(const float* __restrict__ x,
                                        const float* __restrict__ A,
                                        float* __restrict__ slab,
                                        __fp16 (*At)[128][40],
                                        const int* rowid,
                                        int g, int k0, int nsteps, int tz, int n) {
    constexpr int NT  = P2 ? 8 : 2;    // 16-col tiles
    constexpr int NTK = P2 ? 2 : 1;    // staging tasks per thread (2 f4 loads each)

    int t = threadIdx.x, lane = t & 63, w = t >> 6, m = lane & 15, kg = lane >> 4;

    int xr = rowid[16 * w + m];
    const float* xb = x + (size_t)(P2 ? NB1 + xr : xr) * IN_F + k0 + kg * 8;

    // staging task map: (k-pair kp, col group c0); coalesced across lanes in c
    int tkp[NTK], tc0[NTK];
    const float* ap[NTK];
    #pragma unroll
    for (int p = 0; p < NTK; ++p) {
        int tau = P2 ? (t + 256 * p) : (t & 127);
        int kp  = P2 ? (tau >> 5) : (tau >> 3);
        int c4  = P2 ? (tau & 31) : (tau & 7);
        int c0  = 4 * c4;
        tkp[p] = kp; tc0[p] = c0;
        int ad  = P2 ? (32 + 4 * g + (c0 >> 5)) : g;
        ap[p] = A + ((size_t)ad * IN_F + k0 + 2 * kp) * RK + (c0 & 31);
    }

    f4 acc[NT];
    #pragma unroll
    for (int ct = 0; ct < NT; ++ct) acc[ct] = (f4){0.f, 0.f, 0.f, 0.f};

    // prologue: step-0 loads + stage into buf 0
    f4 xf0 = *(const f4*)xb, xf1 = *(const f4*)(xb + 4);
    f4 a0[NTK], a1[NTK];
    #pragma unroll
    for (int p = 0; p < NTK; ++p) { a0[p] = *(const f4*)ap[p]; a1[p] = *(const f4*)(ap[p] + RK); }
    #pragma unroll
    for (int p = 0; p < NTK; ++p) {
        int k = 2 * tkp[p];
        #pragma unroll
        for (int j = 0; j < 4; ++j) {
            int c  = tc0[p] + j;
            int kb = (k >> 3) ^ ((c >> 3) & 3);
            *(h2*)&At[0][c][kb * 8 + (k & 7)] = __builtin_amdgcn_cvt_pkrtz(a0[p][j], a1[p][j]);
        }
    }
    __syncthreads();

    for (int s = 0; s < nsteps; ++s) {
        int  b    = s & 1;
        bool more = (s + 1 < nsteps);
        f4 nx0, nx1, n0[NTK], n1[NTK];
        if (more) {   // issue next-step loads early
            nx0 = *(const f4*)(xb + (size_t)(s + 1) * 32);
            nx1 = *(const f4*)(xb + (size_t)(s + 1) * 32 + 4);
            #pragma unroll
            for (int p = 0; p < NTK; ++p) {
                const float* q = ap[p] + (size_t)(s + 1) * 32 * RK;
                n0[p] = *(const f4*)q; n1[p] = *(const f4*)(q + RK);
            }
        }
        h8 xa;
        {
            union { h8 v8; h2 h[4]; } u;
            u.h[0] = __builtin_amdgcn_cvt_pkrtz(xf0.x, xf0.y);
            u.h[1] = __builtin_amdgcn_cvt_pkrtz(xf0.z, xf0.w);
            u.h[2] = __builtin_amdgcn_cvt_pkrtz(xf1.x, xf1.y);
            u.h[3] = __builtin_amdgcn_cvt_pkrtz(xf1.z, xf1.w);
            xa = u.v8;
        }
        #pragma unroll
        for (int ct = 0; ct < NT; ++ct) {
            int c  = ct * 16 + m;
            int kb = kg ^ ((c >> 3) & 3);
            h8 bf  = *(const h8*)&At[b][c][kb * 8];
            acc[ct] = __builtin_amdgcn_mfma_f32_16x16x32_f16(xa, bf, acc[ct], 0, 0, 0);
        }
        if (more) {   // write next-step staging late
            #pragma unroll
            for (int p = 0; p < NTK; ++p) {
                int k = 2 * tkp[p];
                #pragma unroll
                for (int j = 0; j < 4; ++j) {
                    int c  = tc0[p] + j;
                    int kb = (k >> 3) ^ ((c >> 3) & 3);
                    *(h2*)&At[b ^ 1][c][kb * 8 + (k & 7)] = __builtin_amdgcn_cvt_pkrtz(n0[p][j], n1[p][j]);
                }
            }
            xf0 = nx0; xf1 = nx1;
        }
        __syncthreads();
    }

    // plain stores to this k-chunk's slab (no atomics; tail dups write identical values)
    #pragma unroll
    for (int q = 0; q < 4; ++q) {
        int br = 16 * w + 4 * kg + q;
        int it = 64 * tz + br;
        if (it < n) {
            int rid = rowid[br];
            #pragma unroll
            for (int ct = 0; ct < NT; ++ct) {
                int c = ct * 16 + m;
                size_t off = P2 ? ((size_t)(NB1 + 4 * rid + (c >> 5)) * RK + (c & 31))
                                : ((size_t)rid * RK + c);
                slab[off] = acc[ct][q];
            }
        }
    }
}

__global__ __launch_bounds__(256, 4) void s1_all(const float* __restrict__ x,
                                                 const float* __restrict__ A,
                                                 const int*   __restrict__ cnt,
                                                 const int*   __restrict__ list,
                                                 float*       __restrict__ slabs,
                                                 int nsteps) {
    __shared__ __align__(16) __fp16 At[2][128][40];
    __shared__ int rowid[64];
    int g  = blockIdx.x;     // 0..63: <32 part1 buckets, >=32 part2 groups
    int tz = blockIdx.z;
    int n  = cnt[g];
    if (64 * tz >= n) return;
    if (threadIdx.x < 64) {
        int it = 64 * tz + threadIdx.x;
        rowid[threadIdx.x] = list[g * MAXB + (it < n ? it : n - 1)];
    }
    __syncthreads();
    int k0 = blockIdx.y * nsteps * 32;
    float* slab = slabs + (size_t)blockIdx.y * LRK;
    if (g < 32) s1_body<false>(x, A, slab, At, rowid, g, k0, nsteps, tz, n);
    else        s1_body<true >(x, A, slab, At, rowid, g - 32, k0, nsteps, tz, n);
}

// ---------------- Stage 2: Out[64 x 512] = 2 * (sum_slabs R)[64 x K] @ Bmat[K x 512]
// 4 ot-tiles per block (amortizes slab reduction). Single Bt buffer, 2 barriers
// per phase, next-phase B loads issued between them (overlap MFMA).
template<bool P2>
__device__ __forceinline__ void s2_body(const float* __restrict__ slabs, int nslab,
                                        const float* __restrict__ B,
                                        float* __restrict__ out,
                                        __fp16 (*Bt)[40],
                                        const int* rowid,
                                        int g, int ot0, int tz, int n) {
    constexpr int NS  = P2 ? 4 : 1;
    constexpr int NPH = P2 ? 16 : 4;   // (4 ot tiles) x (NS k-chunks)

    int t = threadIdx.x, lane = t & 63, w = t >> 6, m = lane & 15, kg = lane >> 4;
    int rid0 = rowid[16 * w + m];

    // R fragments: sum slab partials in f32, then round to f16 (matches ref's y rounding)
    h8 rf[NS];
    #pragma unroll
    for (int kc = 0; kc < NS; ++kc) {
        size_t ro = P2 ? (size_t)(NB1 + 4 * rid0 + kc) : (size_t)rid0;
        const float* rp = slabs + ro * RK + kg * 8;
        f4 sa = *(const f4*)rp, sb = *(const f4*)(rp + 4);
        for (int s = 1; s < nslab; ++s) {
            const float* q2 = rp + (size_t)s * LRK;
            sa += *(const f4*)q2; sb += *(const f4*)(q2 + 4);
        }
        h8 f;
        f[0] = (__fp16)sa.x; f[1] = (__fp16)sa.y; f[2] = (__fp16)sa.z; f[3] = (__fp16)sa.w;
        f[4] = (__fp16)sb.x; f[5] = (__fp16)sb.y; f[6] = (__fp16)sb.z; f[7] = (__fp16)sb.w;
        rf[kc] = f;
    }

    int oc = t & 127, kh = t >> 7;

    float v[16], vn[16];
    {
        int a = P2 ? (32 + 4 * g) : g;
        const float* s0 = B + ((size_t)a * RK + kh * 16) * OUT_F + (size_t)ot0 * 128 + oc;
        #pragma unroll
        for (int q = 0; q < 16; ++q) v[q] = s0[q * OUT_F];
    }

    f4 acc[8];
    #pragma unroll
    for (int ct = 0; ct < 8; ++ct) acc[ct] = (f4){0.f, 0.f, 0.f, 0.f};

    #pragma unroll
    for (int ph = 0; ph < NPH; ++ph) {
        int oti = P2 ? (ph >> 2) : ph;
        int kc  = P2 ? (ph & 3) : 0;
        __syncthreads();                       // Bt free (prev MFMAs done)
        #pragma unroll
        for (int q = 0; q < 8; ++q)
            *(h2*)&Bt[oc][kh * 16 + 2 * q] = __builtin_amdgcn_cvt_pkrtz(v[2 * q], v[2 * q + 1]);
        if (ph + 1 < NPH) {                    // issue next-phase loads early
            int noti = P2 ? ((ph + 1) >> 2) : (ph + 1);
            int nkc  = P2 ? ((ph + 1) & 3) : 0;
            int a = P2 ? (32 + 4 * g + nkc) : g;
            const float* sn = B + ((size_t)a * RK + kh * 16) * OUT_F + (size_t)(ot0 + noti) * 128 + oc;
            #pragma unroll
            for (int q = 0; q < 16; ++q) vn[q] = sn[q * OUT_F];
        }
        __syncthreads();                       // Bt ready
        #pragma unroll
        for (int ct = 0; ct < 8; ++ct) {
            h8 bf = *(const h8*)&Bt[ct * 16 + m][kg * 8];
            acc[ct] = __builtin_amdgcn_mfma_f32_16x16x32_f16(rf[kc], bf, acc[ct], 0, 0, 0);
        }
        if (kc == NS - 1) {                    // flush this ot tile
            #pragma unroll
            for (int q = 0; q < 4; ++q) {
                int br = 16 * w + 4 * kg + q;
                int it = 64 * tz + br;
                if (it < n) {
                    int orow = P2 ? (NB1 + rowid[br]) : rowid[br];
                    float* op = out + (size_t)orow * OUT_F + (size_t)(ot0 + oti) * 128 + m;
                    #pragma unroll
                    for (int ct = 0; ct < 8; ++ct)
                        op[ct * 16] = 2.f * acc[ct][q];
                }
            }
            #pragma unroll
            for (int ct = 0; ct < 8; ++ct) acc[ct] = (f4){0.f, 0.f, 0.f, 0.f};
        }
        #pragma unroll
        for (int q = 0; q < 16; ++q) v[q] = vn[q];
    }
}

__global__ __launch_bounds__(256, 3) void s2_all(const float* __restrict__ slabs,
                                                 int nslab,
                                                 const float* __restrict__ B,
                                                 const int*   __restrict__ cnt,
                                                 const int*   __restrict__ list,
                                                 float*       __restrict__ out) {
    __shared__ __align__(16) __fp16 Bt[128][40];
    __shared__ int rowid[64];
    int g   = blockIdx.x;
    int ot0 = blockIdx.y * 4;     // 4 x 128-col tiles per block
    int tz  = blockIdx.z;
    int n   = cnt[g];
    if (64 * tz >= n) return;
    if (threadIdx.x < 64) {
        int it = 64 * tz + threadIdx.x;
        rowid[threadIdx.x] = list[g * MAXB + (it < n ? it : n - 1)];
    }
    __syncthreads();
    if (g < 32) s2_body<false>(slabs, nslab, B, out, Bt, rowid, g, ot0, tz, n);
    else        s2_body<true >(slabs, nslab, B, out, Bt, rowid, g - 32, ot0, tz, n);
}

extern "C" void kernel_launch(void* const* d_in, const int* in_sizes, int n_in,
                              void* d_out, int out_size, void* d_ws, size_t ws_size,
                              hipStream_t stream) {
    const float* x    = (const float*)d_in[0];
    const int*   wids = (const int*)  d_in[2];
    const float* A    = (const float*)d_in[3];
    const float* Bm   = (const float*)d_in[4];
    float* out = (float*)d_out;

    int* wsI  = (int*)d_ws;
    int* cnt  = wsI;
    int* list = wsI + 64;
    float* slabs = (float*)(list + 64 * MAXB);

    size_t fixed = (size_t)(64 + 64 * MAXB) * sizeof(int);
    int ks = 8;   // k-split: slabs must fit in ws
    while (ks > 1 && fixed + (size_t)ks * LRK * sizeof(float) > ws_size) ks >>= 1;
    int nsteps = 128 / ks;   // 32-k steps per s1 block

    bin_rows<<<dim3(1), dim3(1024), 0, stream>>>(wids, cnt, list);
    s1_all<<<dim3(64, ks, TILES), dim3(256), 0, stream>>>(x, A, cnt, list, slabs, nsteps);
    s2_all<<<dim3(64, 8, TILES), dim3(256), 0, stream>>>(slabs, ks, Bm, cnt, list, out);
}